// Round 1
// baseline (431.188 us; speedup 1.0000x reference)
//
#include <hip/hip_runtime.h>
#include <stdint.h>

// ---- problem constants ----
constexpr int NBASES = 32;
constexpr int NKP    = 17;
constexpr int HDIM   = 100, WDIM = 152;
constexpr int HW     = HDIM * WDIM;       // 15200
constexpr int NI     = 64;                 // n_inst
constexpr int KF     = 2304;               // 256*9
constexpr int AL     = 2737;               // ATTN_LEN
// split offsets inside attns row
constexpr int OW0 = 0;      // 32x34
constexpr int OB0 = 1088;   // 32
constexpr int OW1 = 1120;   // 32x32
constexpr int OB1 = 2144;   // 32
constexpr int OW2 = 2176;   // 17x32
constexpr int OB2 = 2720;   // 17

// ================= kernel 0: init attns with bias =================
__global__ __launch_bounds__(256) void init_attn(const float* __restrict__ b,
                                                 float* __restrict__ attns) {
    int i = blockIdx.x * 256 + threadIdx.x;
    if (i < NI * AL) attns[i] = b[i % AL];
}

// ================= kernel 1: attns GEMM (64x2737 = tf @ W^T) =================
constexpr int JT     = 64;            // j per block
constexpr int KCH    = 64;            // k chunk staged per iteration
constexpr int KSPLIT = 6;             // k-splits -> KT = 384
constexpr int KT     = KF / KSPLIT;   // 384
constexpr int NJT    = (AL + JT - 1) / JT;  // 43

__global__ __launch_bounds__(256) void gemm_attn(const float* __restrict__ tf,
                                                 const float* __restrict__ W,
                                                 float* __restrict__ attns) {
    __shared__ float Wl[JT][KCH + 1];
    __shared__ float Tl[NI][KCH + 1];
    int jb = blockIdx.x % NJT;
    int ks = blockIdx.x / NJT;
    int j0 = jb * JT;
    int k0 = ks * KT;
    int tid = threadIdx.x;
    int tn = tid % 16;   // n tile: 4 rows starting at 4*tn
    int tj = tid / 16;   // j tile: 4 cols starting at 4*tj
    float acc[4][4] = {};
    int lc = tid % 64;
    int lr = tid / 64;
    for (int kc = 0; kc < KT; kc += KCH) {
        int kbase = k0 + kc;
        #pragma unroll
        for (int r = lr; r < JT; r += 4) {
            int j = j0 + r;
            Wl[r][lc] = (j < AL) ? W[(size_t)j * KF + kbase + lc] : 0.0f;
        }
        #pragma unroll
        for (int r = lr; r < NI; r += 4) {
            Tl[r][lc] = tf[(size_t)r * KF + kbase + lc];
        }
        __syncthreads();
        for (int kk = 0; kk < KCH; ++kk) {
            float tv[4], wv[4];
            #pragma unroll
            for (int i = 0; i < 4; i++) tv[i] = Tl[tn * 4 + i][kk];
            #pragma unroll
            for (int i = 0; i < 4; i++) wv[i] = Wl[tj * 4 + i][kk];
            #pragma unroll
            for (int i = 0; i < 4; i++)
                #pragma unroll
                for (int q = 0; q < 4; q++) acc[i][q] += tv[i] * wv[q];
        }
        __syncthreads();
    }
    #pragma unroll
    for (int i = 0; i < 4; i++) {
        int n = tn * 4 + i;
        #pragma unroll
        for (int q = 0; q < 4; q++) {
            int j = j0 + tj * 4 + q;
            if (j < AL) atomicAdd(&attns[(size_t)n * AL + j], acc[i][q]);
        }
    }
}

// ================= kernel 2: fused per-pixel head =================
__global__ __launch_bounds__(256) void pixel_head(const float* __restrict__ bases_full,
                                                  const float* __restrict__ attns,
                                                  const float* __restrict__ locations,
                                                  const float* __restrict__ soi,
                                                  const int* __restrict__ fpn,
                                                  float* __restrict__ out_logits) {
    __shared__ float w[AL];
    int n = blockIdx.y;
    const float* an = attns + (size_t)n * AL;
    for (int i = threadIdx.x; i < AL; i += 256) w[i] = an[i];
    __syncthreads();

    int p = blockIdx.x * 256 + threadIdx.x;
    bool valid = p < HW;
    int pp = valid ? p : (HW - 1);
    int y = pp / WDIM;
    int x = pp - y * WDIM;

    float inv = 1.0f / soi[fpn[n]];
    float lx = locations[2 * n + 0];
    float ly = locations[2 * n + 1];

    float x0[34];
    x0[0] = (lx - (float)(x * 8 + 4)) * inv;
    x0[1] = (ly - (float)(y * 8 + 4)) * inv;
    #pragma unroll
    for (int c = 0; c < 32; c++) x0[2 + c] = bases_full[(size_t)c * HW + pp];

    float h0[32];
    #pragma unroll
    for (int o = 0; o < 32; o++) {
        float s = w[OB0 + o];
        #pragma unroll
        for (int c = 0; c < 34; c++) s += w[OW0 + o * 34 + c] * x0[c];
        h0[o] = s > 0.0f ? s : 0.0f;
    }
    float h1[32];
    #pragma unroll
    for (int o = 0; o < 32; o++) {
        float s = w[OB1 + o];
        #pragma unroll
        for (int c = 0; c < 32; c++) s += w[OW1 + o * 32 + c] * h0[c];
        h1[o] = s > 0.0f ? s : 0.0f;
    }
    size_t base = (size_t)n * NKP * HW;
    #pragma unroll
    for (int k = 0; k < NKP; k++) {
        float s = w[OB2 + k];
        #pragma unroll
        for (int c = 0; c < 32; c++) s += w[OW2 + k * 32 + c] * h1[c];
        if (valid) out_logits[base + (size_t)k * HW + p] = s;
    }
}

// ================= kernel 3: per-(n,k) argmax + keypoint =================
__device__ inline unsigned int mono_f32(float f) {
    unsigned int u = __float_as_uint(f);
    return (u & 0x80000000u) ? ~u : (u | 0x80000000u);
}

__global__ __launch_bounds__(256) void argmax_kp(const float* __restrict__ logits,
                                                 const float* __restrict__ bases_full,
                                                 float* __restrict__ kp_out) {
    int n = blockIdx.x / NKP;
    int k = blockIdx.x % NKP;
    const float* row = logits + ((size_t)n * NKP + k) * HW;

    float bestv = -__builtin_inff();
    int bestp = 0;
    for (int p = threadIdx.x; p < HW; p += 256) {
        float v = row[p];
        if (v > bestv) { bestv = v; bestp = p; }
    }
    unsigned long long packed =
        ((unsigned long long)mono_f32(bestv) << 32) |
        (unsigned long long)(0xFFFFFFFFu - (unsigned)bestp);

    #pragma unroll
    for (int off = 32; off > 0; off >>= 1) {
        unsigned long long o = __shfl_down(packed, off, 64);
        if (o > packed) packed = o;
    }
    __shared__ unsigned long long red[4];
    int lane = threadIdx.x & 63;
    int wid  = threadIdx.x >> 6;
    if (lane == 0) red[wid] = packed;
    __syncthreads();
    if (threadIdx.x == 0) {
        #pragma unroll
        for (int i = 1; i < 4; i++)
            if (red[i] > packed) packed = red[i];
        int p = (int)(0xFFFFFFFFu - (unsigned)(packed & 0xFFFFFFFFull));
        int yy = p / WDIM;
        int xx = p - yy * WDIM;
        float kx = bases_full[(size_t)(NBASES + 2 * k) * HW + p] + (float)(xx * 8 + 4);
        float ky = bases_full[(size_t)(NBASES + 2 * k + 1) * HW + p] + (float)(yy * 8 + 4);
        kp_out[((size_t)n * NKP + k) * 2 + 0] = kx;
        kp_out[((size_t)n * NKP + k) * 2 + 1] = ky;
    }
}

extern "C" void kernel_launch(void* const* d_in, const int* in_sizes, int n_in,
                              void* d_out, int out_size, void* d_ws, size_t ws_size,
                              hipStream_t stream) {
    const float* bases_full = (const float*)d_in[0];
    const float* top_feats  = (const float*)d_in[1];
    const float* locations  = (const float*)d_in[2];
    const float* atten_W    = (const float*)d_in[3];
    const float* atten_b    = (const float*)d_in[4];
    const float* soi        = (const float*)d_in[5];
    const int*   fpn        = (const int*)d_in[6];
    float* out   = (float*)d_out;
    float* attns = (float*)d_ws;   // 64*2737 floats

    init_attn<<<(NI * AL + 255) / 256, 256, 0, stream>>>(atten_b, attns);
    gemm_attn<<<NJT * KSPLIT, 256, 0, stream>>>(top_feats, atten_W, attns);

    dim3 g2((HW + 255) / 256, NI);
    pixel_head<<<g2, 256, 0, stream>>>(bases_full, attns, locations, soi, fpn, out);

    float* kp_out = out + (size_t)NI * NKP * HW;
    argmax_kp<<<NI * NKP, 256, 0, stream>>>(out, bases_full, kp_out);
}

// Round 2
// 426.442 us; speedup vs baseline: 1.0111x; 1.0111x over previous
//
#include <hip/hip_runtime.h>
#include <stdint.h>

// ---- problem constants ----
constexpr int NBASES = 32;
constexpr int NKP    = 17;
constexpr int HDIM   = 100, WDIM = 152;
constexpr int HW     = HDIM * WDIM;       // 15200
constexpr int NI     = 64;                 // n_inst
constexpr int KF     = 2304;               // 256*9
constexpr int AL     = 2737;               // ATTN_LEN
// split offsets inside attns row (packed reference layout)
constexpr int OW0 = 0;      // 32x34
constexpr int OB0 = 1088;   // 32
constexpr int OW1 = 1120;   // 32x32
constexpr int OB1 = 2144;   // 32
constexpr int OW2 = 2176;   // 17x32
constexpr int OB2 = 2720;   // 17
// padded LDS layout for pixel_head (W0 rows padded 34->36 so each row is 16B-aligned)
constexpr int PW0 = 0;      // 32 x 36 = 1152
constexpr int PB0 = 1152;   // 32
constexpr int PW1 = 1184;   // 32 x 32 = 1024  (1184*4 % 16 == 0)
constexpr int PB1 = 2208;   // 32
constexpr int PW2 = 2240;   // 17 x 32 = 544   (2240*4 % 16 == 0)
constexpr int PB2 = 2784;   // 17
constexpr int PTOT = 2804;

// ================= kernel 0: init attns with bias =================
__global__ __launch_bounds__(256) void init_attn(const float* __restrict__ b,
                                                 float* __restrict__ attns) {
    int i = blockIdx.x * 256 + threadIdx.x;
    if (i < NI * AL) attns[i] = b[i % AL];
}

// ================= kernel 1: attns GEMM (64x2737 = tf @ W^T) =================
constexpr int JT     = 64;             // j per block
constexpr int KCH    = 64;             // k chunk staged per iteration
constexpr int KSPLIT = 12;             // k-splits -> KT = 192
constexpr int KT     = KF / KSPLIT;    // 192
constexpr int NJT    = (AL + JT - 1) / JT;  // 43
constexpr int LPAD   = 68;             // row stride (floats): 16B-aligned rows

__global__ __launch_bounds__(256) void gemm_attn(const float* __restrict__ tf,
                                                 const float* __restrict__ W,
                                                 float* __restrict__ attns) {
    // k-major layout: fragment reads are contiguous -> ds_read_b128
    __shared__ __align__(16) float Tl[KCH][LPAD];
    __shared__ __align__(16) float Wl[KCH][LPAD];
    int jb = blockIdx.x % NJT;
    int ks = blockIdx.x / NJT;
    int j0 = jb * JT;
    int k0 = ks * KT;
    int tid = threadIdx.x;
    int tn = tid % 16;   // n tile: 4 rows starting at 4*tn
    int tj = tid / 16;   // j tile: 4 cols starting at 4*tj
    int lk = tid % 64;   // k lane for staging
    int lr = tid / 64;   // 0..3
    float acc[4][4] = {};
    for (int kc = 0; kc < KT; kc += KCH) {
        int kbase = k0 + kc;
        // stage: global row-coalesced (consecutive lanes read consecutive k),
        // LDS write transposed into k-major
        #pragma unroll
        for (int i = 0; i < 16; i++) {
            int n = lr * 16 + i;
            Tl[lk][n] = tf[(size_t)n * KF + kbase + lk];
        }
        #pragma unroll
        for (int i = 0; i < 16; i++) {
            int j = j0 + lr * 16 + i;
            Wl[lk][lr * 16 + i] = (j < AL) ? W[(size_t)j * KF + kbase + lk] : 0.0f;
        }
        __syncthreads();
        #pragma unroll 4
        for (int kk = 0; kk < KCH; ++kk) {
            float tv[4], wv[4];
            #pragma unroll
            for (int i = 0; i < 4; i++) tv[i] = Tl[kk][tn * 4 + i];   // b128
            #pragma unroll
            for (int i = 0; i < 4; i++) wv[i] = Wl[kk][tj * 4 + i];   // b128
            #pragma unroll
            for (int i = 0; i < 4; i++)
                #pragma unroll
                for (int q = 0; q < 4; q++) acc[i][q] += tv[i] * wv[q];
        }
        __syncthreads();
    }
    #pragma unroll
    for (int i = 0; i < 4; i++) {
        int n = tn * 4 + i;
        #pragma unroll
        for (int q = 0; q < 4; q++) {
            int j = j0 + tj * 4 + q;
            if (j < AL) atomicAdd(&attns[(size_t)n * AL + j], acc[i][q]);
        }
    }
}

// ================= kernel 2: fused per-pixel head (2 px / thread) =================
__global__ __launch_bounds__(256, 2) void pixel_head(const float* __restrict__ bases_full,
                                                     const float* __restrict__ attns,
                                                     const float* __restrict__ locations,
                                                     const float* __restrict__ soi,
                                                     const int* __restrict__ fpn,
                                                     float* __restrict__ out_logits) {
    __shared__ __align__(16) float w[PTOT];
    int n = blockIdx.y;
    {
        const float* an = attns + (size_t)n * AL;
        for (int i = threadIdx.x; i < AL; i += 256) {
            float v = an[i];
            int d;
            if (i < OB0)      { int o = i / 34; d = PW0 + o * 36 + (i - o * 34); }
            else if (i < OW1) d = PB0 + (i - OB0);
            else if (i < OB1) d = PW1 + (i - OW1);
            else if (i < OW2) d = PB1 + (i - OB1);
            else if (i < OB2) d = PW2 + (i - OW2);
            else              d = PB2 + (i - OB2);
            w[d] = v;
        }
    }
    __syncthreads();

    int p0 = blockIdx.x * 512 + threadIdx.x;   // always < HW (29*512+255 = 15103)
    int p1 = p0 + 256;
    bool v1 = p1 < HW;
    int q1 = v1 ? p1 : (HW - 1);

    int y0 = p0 / WDIM, x0i = p0 - y0 * WDIM;
    int y1 = q1 / WDIM, x1i = q1 - y1 * WDIM;

    float inv = 1.0f / soi[fpn[n]];
    float lx = locations[2 * n + 0];
    float ly = locations[2 * n + 1];

    float xa[34], xb[34];
    xa[0] = (lx - (float)(x0i * 8 + 4)) * inv;
    xa[1] = (ly - (float)(y0 * 8 + 4)) * inv;
    xb[0] = (lx - (float)(x1i * 8 + 4)) * inv;
    xb[1] = (ly - (float)(y1 * 8 + 4)) * inv;
    #pragma unroll
    for (int c = 0; c < 32; c++) {
        xa[2 + c] = bases_full[(size_t)c * HW + p0];
        xb[2 + c] = bases_full[(size_t)c * HW + q1];
    }

    float ha[32], hb[32];
    #pragma unroll
    for (int o = 0; o < 32; o++) {
        float sa = w[PB0 + o], sb = sa;
        #pragma unroll
        for (int c = 0; c < 34; c++) {
            float wv = w[PW0 + o * 36 + c];
            sa += wv * xa[c];
            sb += wv * xb[c];
        }
        ha[o] = sa > 0.0f ? sa : 0.0f;
        hb[o] = sb > 0.0f ? sb : 0.0f;
    }
    float ga[32], gb[32];
    #pragma unroll
    for (int o = 0; o < 32; o++) {
        float sa = w[PB1 + o], sb = sa;
        #pragma unroll
        for (int c = 0; c < 32; c++) {
            float wv = w[PW1 + o * 32 + c];
            sa += wv * ha[c];
            sb += wv * hb[c];
        }
        ga[o] = sa > 0.0f ? sa : 0.0f;
        gb[o] = sb > 0.0f ? sb : 0.0f;
    }
    size_t base = (size_t)n * NKP * HW;
    #pragma unroll
    for (int k = 0; k < NKP; k++) {
        float sa = w[PB2 + k], sb = sa;
        #pragma unroll
        for (int c = 0; c < 32; c++) {
            float wv = w[PW2 + k * 32 + c];
            sa += wv * ga[c];
            sb += wv * gb[c];
        }
        out_logits[base + (size_t)k * HW + p0] = sa;
        if (v1) out_logits[base + (size_t)k * HW + p1] = sb;
    }
}

// ================= kernel 3: per-(n,k) argmax + keypoint =================
__device__ inline unsigned int mono_f32(float f) {
    unsigned int u = __float_as_uint(f);
    return (u & 0x80000000u) ? ~u : (u | 0x80000000u);
}

__global__ __launch_bounds__(256) void argmax_kp(const float* __restrict__ logits,
                                                 const float* __restrict__ bases_full,
                                                 float* __restrict__ kp_out) {
    int n = blockIdx.x / NKP;
    int k = blockIdx.x % NKP;
    const float* row = logits + ((size_t)n * NKP + k) * HW;

    float bestv = -__builtin_inff();
    int bestp = 0;
    for (int p = threadIdx.x; p < HW; p += 256) {
        float v = row[p];
        if (v > bestv) { bestv = v; bestp = p; }
    }
    unsigned long long packed =
        ((unsigned long long)mono_f32(bestv) << 32) |
        (unsigned long long)(0xFFFFFFFFu - (unsigned)bestp);

    #pragma unroll
    for (int off = 32; off > 0; off >>= 1) {
        unsigned long long o = __shfl_down(packed, off, 64);
        if (o > packed) packed = o;
    }
    __shared__ unsigned long long red[4];
    int lane = threadIdx.x & 63;
    int wid  = threadIdx.x >> 6;
    if (lane == 0) red[wid] = packed;
    __syncthreads();
    if (threadIdx.x == 0) {
        #pragma unroll
        for (int i = 1; i < 4; i++)
            if (red[i] > packed) packed = red[i];
        int p = (int)(0xFFFFFFFFu - (unsigned)(packed & 0xFFFFFFFFull));
        int yy = p / WDIM;
        int xx = p - yy * WDIM;
        float kx = bases_full[(size_t)(NBASES + 2 * k) * HW + p] + (float)(xx * 8 + 4);
        float ky = bases_full[(size_t)(NBASES + 2 * k + 1) * HW + p] + (float)(yy * 8 + 4);
        kp_out[((size_t)n * NKP + k) * 2 + 0] = kx;
        kp_out[((size_t)n * NKP + k) * 2 + 1] = ky;
    }
}

extern "C" void kernel_launch(void* const* d_in, const int* in_sizes, int n_in,
                              void* d_out, int out_size, void* d_ws, size_t ws_size,
                              hipStream_t stream) {
    const float* bases_full = (const float*)d_in[0];
    const float* top_feats  = (const float*)d_in[1];
    const float* locations  = (const float*)d_in[2];
    const float* atten_W    = (const float*)d_in[3];
    const float* atten_b    = (const float*)d_in[4];
    const float* soi        = (const float*)d_in[5];
    const int*   fpn        = (const int*)d_in[6];
    float* out   = (float*)d_out;
    float* attns = (float*)d_ws;   // 64*2737 floats

    init_attn<<<(NI * AL + 255) / 256, 256, 0, stream>>>(atten_b, attns);
    gemm_attn<<<NJT * KSPLIT, 256, 0, stream>>>(top_feats, atten_W, attns);

    dim3 g2((HW + 511) / 512, NI);   // 30 x 64
    pixel_head<<<g2, 256, 0, stream>>>(bases_full, attns, locations, soi, fpn, out);

    float* kp_out = out + (size_t)NI * NKP * HW;
    argmax_kp<<<NI * NKP, 256, 0, stream>>>(out, bases_full, kp_out);
}

// Round 3
// 283.568 us; speedup vs baseline: 1.5206x; 1.5038x over previous
//
#include <hip/hip_runtime.h>
#include <stdint.h>

// ---- problem constants ----
constexpr int NBASES = 32;
constexpr int NKP    = 17;
constexpr int HDIM   = 100, WDIM = 152;
constexpr int HW     = HDIM * WDIM;       // 15200
constexpr int NI     = 64;
constexpr int KF     = 2304;
constexpr int AL     = 2737;
// packed reference offsets inside an attns row
constexpr int OB0 = 1088;   // after 32x34 w0
constexpr int OW1 = 1120;
constexpr int OB1 = 2144;
constexpr int OW2 = 2176;
constexpr int OB2 = 2720;
// LDS layout (w0/w1 transposed c-major so per-c rows are o-contiguous, 16B-aligned)
constexpr int TW0 = 0;      // [34][32]
constexpr int TB0 = 1088;   // 32
constexpr int TW1 = 1120;   // [32][32]
constexpr int TB1 = 2144;   // 32
constexpr int TW2 = 2176;   // [17][32] k-major rows (same as reference)
constexpr int TB2 = 2720;   // 17
constexpr int WTOT = 2737;

constexpr int PXB = 512;                     // pixels per block (256 thr x 2 px)
constexpr int NBX = (HW + PXB - 1) / PXB;    // 30
// ws layout: attns floats at 0 (700,672 B); partials (ulong) at byte 917504
constexpr size_t PART_OFF = 917504;

// ================= kernel 0: init attns with bias =================
__global__ __launch_bounds__(256) void init_attn(const float* __restrict__ b,
                                                 float* __restrict__ attns) {
    int i = blockIdx.x * 256 + threadIdx.x;
    if (i < NI * AL) attns[i] = b[i % AL];
}

// ================= kernel 1: attns GEMM (64x2737 = tf @ W^T) =================
constexpr int JT     = 64;
constexpr int KCH    = 64;
constexpr int KSPLIT = 6;              // KT = 384
constexpr int KT     = KF / KSPLIT;
constexpr int NJT    = (AL + JT - 1) / JT;  // 43
constexpr int LPAD   = 68;

__global__ __launch_bounds__(256) void gemm_attn(const float* __restrict__ tf,
                                                 const float* __restrict__ W,
                                                 float* __restrict__ attns) {
    __shared__ __align__(16) float Tl[KCH][LPAD];
    __shared__ __align__(16) float Wl[KCH][LPAD];
    int jb = blockIdx.x % NJT;
    int ks = blockIdx.x / NJT;
    int j0 = jb * JT;
    int k0 = ks * KT;
    int tid = threadIdx.x;
    int tn = tid % 16;
    int tj = tid / 16;
    int lk = tid % 64;
    int lr = tid / 64;
    float acc[4][4] = {};
    for (int kc = 0; kc < KT; kc += KCH) {
        int kbase = k0 + kc;
        #pragma unroll
        for (int i = 0; i < 16; i++) {
            int n = lr * 16 + i;
            Tl[lk][n] = tf[(size_t)n * KF + kbase + lk];
        }
        #pragma unroll
        for (int i = 0; i < 16; i++) {
            int j = j0 + lr * 16 + i;
            Wl[lk][lr * 16 + i] = (j < AL) ? W[(size_t)j * KF + kbase + lk] : 0.0f;
        }
        __syncthreads();
        #pragma unroll 4
        for (int kk = 0; kk < KCH; ++kk) {
            float tv[4], wv[4];
            #pragma unroll
            for (int i = 0; i < 4; i++) tv[i] = Tl[kk][tn * 4 + i];
            #pragma unroll
            for (int i = 0; i < 4; i++) wv[i] = Wl[kk][tj * 4 + i];
            #pragma unroll
            for (int i = 0; i < 4; i++)
                #pragma unroll
                for (int q = 0; q < 4; q++) acc[i][q] += tv[i] * wv[q];
        }
        __syncthreads();
    }
    #pragma unroll
    for (int i = 0; i < 4; i++) {
        int n = tn * 4 + i;
        #pragma unroll
        for (int q = 0; q < 4; q++) {
            int j = j0 + tj * 4 + q;
            if (j < AL) atomicAdd(&attns[(size_t)n * AL + j], acc[i][q]);
        }
    }
}

// ================= kernel 2: fused per-pixel head + block argmax =================
__device__ inline unsigned int mono_f32(float f) {
    unsigned int u = __float_as_uint(f);
    return (u & 0x80000000u) ? ~u : (u | 0x80000000u);
}

__global__ __launch_bounds__(256) void pixel_head(const float* __restrict__ bases_full,
                                                  const float* __restrict__ attns,
                                                  const float* __restrict__ locations,
                                                  const float* __restrict__ soi,
                                                  const int* __restrict__ fpn,
                                                  float* __restrict__ out_logits,
                                                  unsigned long long* __restrict__ partial) {
    __shared__ __align__(16) float w[WTOT];
    __shared__ unsigned long long red[4][NKP];
    int n = blockIdx.y, bx = blockIdx.x, tid = threadIdx.x;

    {   // stage + permute weights into LDS (w0/w1 transposed c-major)
        const float* an = attns + (size_t)n * AL;
        for (int i = tid; i < AL; i += 256) {
            float v = an[i];
            int d;
            if (i < OB0)      { int o = i / 34, c = i - o * 34; d = TW0 + c * 32 + o; }
            else if (i < OW1) d = TB0 + (i - OB0);
            else if (i < OB1) { int j = i - OW1; int o = j >> 5, c = j & 31; d = TW1 + c * 32 + o; }
            else if (i < OW2) d = TB1 + (i - OB1);
            else if (i < OB2) d = TW2 + (i - OW2);
            else              d = TB2 + (i - OB2);
            w[d] = v;
        }
    }
    __syncthreads();

    int p0 = bx * PXB + tid * 2;
    bool valid = p0 < HW;
    int pc = valid ? p0 : 0;
    int y = pc / WDIM, x = pc - y * WDIM;

    float inv = 1.0f / soi[fpn[n]];
    float lx = locations[2 * n], ly = locations[2 * n + 1];
    float cxa = (lx - (float)(x * 8 + 4)) * inv;
    float cxb = (lx - (float)(x * 8 + 12)) * inv;   // next pixel, same row
    float cyy = (ly - (float)(y * 8 + 4)) * inv;

    // ---- layer 0: h = relu(W0 x + b0), c-outer streaming ----
    float ha[32], hb[32];
    {
        const float4* br = (const float4*)&w[TB0];
        #pragma unroll
        for (int g = 0; g < 8; g++) {
            float4 b4 = br[g];
            ha[4*g+0] = b4.x; ha[4*g+1] = b4.y; ha[4*g+2] = b4.z; ha[4*g+3] = b4.w;
        }
        #pragma unroll
        for (int o = 0; o < 32; o++) hb[o] = ha[o];
        const float4* w0r = (const float4*)&w[TW0 + 0 * 32];
        const float4* w1r = (const float4*)&w[TW0 + 1 * 32];
        #pragma unroll
        for (int g = 0; g < 8; g++) {
            float4 wv = w0r[g], wu = w1r[g];
            ha[4*g+0] += wv.x * cxa + wu.x * cyy;  hb[4*g+0] += wv.x * cxb + wu.x * cyy;
            ha[4*g+1] += wv.y * cxa + wu.y * cyy;  hb[4*g+1] += wv.y * cxb + wu.y * cyy;
            ha[4*g+2] += wv.z * cxa + wu.z * cyy;  hb[4*g+2] += wv.z * cxb + wu.z * cyy;
            ha[4*g+3] += wv.w * cxa + wu.w * cyy;  hb[4*g+3] += wv.w * cxb + wu.w * cyy;
        }
    }
    #pragma unroll 4
    for (int c = 0; c < 32; c++) {
        float2 bv = *(const float2*)&bases_full[(size_t)c * HW + pc];
        const float4* wr = (const float4*)&w[TW0 + (c + 2) * 32];
        #pragma unroll
        for (int g = 0; g < 8; g++) {
            float4 wv = wr[g];
            ha[4*g+0] += wv.x * bv.x;  hb[4*g+0] += wv.x * bv.y;
            ha[4*g+1] += wv.y * bv.x;  hb[4*g+1] += wv.y * bv.y;
            ha[4*g+2] += wv.z * bv.x;  hb[4*g+2] += wv.z * bv.y;
            ha[4*g+3] += wv.w * bv.x;  hb[4*g+3] += wv.w * bv.y;
        }
    }
    #pragma unroll
    for (int o = 0; o < 32; o++) {
        ha[o] = fmaxf(ha[o], 0.0f);
        hb[o] = fmaxf(hb[o], 0.0f);
    }

    // ---- layer 1: g = relu(W1 h + b1), c-outer streaming ----
    float ga[32], gb[32];
    {
        const float4* br = (const float4*)&w[TB1];
        #pragma unroll
        for (int g = 0; g < 8; g++) {
            float4 b4 = br[g];
            ga[4*g+0] = b4.x; ga[4*g+1] = b4.y; ga[4*g+2] = b4.z; ga[4*g+3] = b4.w;
        }
        #pragma unroll
        for (int o = 0; o < 32; o++) gb[o] = ga[o];
    }
    #pragma unroll 4
    for (int c = 0; c < 32; c++) {
        float xa = ha[c], xb = hb[c];
        const float4* wr = (const float4*)&w[TW1 + c * 32];
        #pragma unroll
        for (int g = 0; g < 8; g++) {
            float4 wv = wr[g];
            ga[4*g+0] += wv.x * xa;  gb[4*g+0] += wv.x * xb;
            ga[4*g+1] += wv.y * xa;  gb[4*g+1] += wv.y * xb;
            ga[4*g+2] += wv.z * xa;  gb[4*g+2] += wv.z * xb;
            ga[4*g+3] += wv.w * xa;  gb[4*g+3] += wv.w * xb;
        }
    }
    #pragma unroll
    for (int o = 0; o < 32; o++) {
        ga[o] = fmaxf(ga[o], 0.0f);
        gb[o] = fmaxf(gb[o], 0.0f);
    }

    // ---- layer 2 (17 outputs): store logits + fused per-k argmax ----
    size_t obase = (size_t)n * NKP * HW;
    int wid = tid >> 6, lane = tid & 63;
    #pragma unroll
    for (int k = 0; k < NKP; k++) {
        const float4* wr = (const float4*)&w[TW2 + k * 32];
        float sa = w[TB2 + k], sb = sa;
        #pragma unroll
        for (int g = 0; g < 8; g++) {
            float4 wv = wr[g];
            sa += wv.x * ga[4*g+0] + wv.y * ga[4*g+1] + wv.z * ga[4*g+2] + wv.w * ga[4*g+3];
            sb += wv.x * gb[4*g+0] + wv.y * gb[4*g+1] + wv.z * gb[4*g+2] + wv.w * gb[4*g+3];
        }
        unsigned long long pk = 0;
        if (valid) {
            *(float2*)&out_logits[obase + (size_t)k * HW + p0] = make_float2(sa, sb);
            float bv = sa; int bp = p0;
            if (sb > sa) { bv = sb; bp = p0 + 1; }   // tie -> smaller index (numpy)
            pk = ((unsigned long long)mono_f32(bv) << 32) |
                 (unsigned long long)(0xFFFFFFFFu - (unsigned)bp);
        }
        #pragma unroll
        for (int off = 32; off > 0; off >>= 1) {
            unsigned long long o = __shfl_down(pk, off);
            if (o > pk) pk = o;
        }
        if (lane == 0) red[wid][k] = pk;
    }
    __syncthreads();
    if (tid < NKP) {
        unsigned long long m = red[0][tid];
        #pragma unroll
        for (int ww = 1; ww < 4; ww++)
            if (red[ww][tid] > m) m = red[ww][tid];
        partial[((size_t)n * NKP + tid) * NBX + bx] = m;
    }
}

// ================= kernel 3: final argmax reduce + keypoint =================
__global__ __launch_bounds__(64) void kp_final(const unsigned long long* __restrict__ partial,
                                               const float* __restrict__ bases_full,
                                               float* __restrict__ kp_out) {
    int b = blockIdx.x;
    int n = b / NKP, k = b % NKP;
    int lane = threadIdx.x;
    unsigned long long v = (lane < NBX) ? partial[((size_t)n * NKP + k) * NBX + lane] : 0ull;
    #pragma unroll
    for (int off = 32; off > 0; off >>= 1) {
        unsigned long long o = __shfl_down(v, off);
        if (o > v) v = o;
    }
    if (lane == 0) {
        int p = (int)(0xFFFFFFFFu - (unsigned)(v & 0xFFFFFFFFull));
        int yy = p / WDIM;
        int xx = p - yy * WDIM;
        float kx = bases_full[(size_t)(NBASES + 2 * k) * HW + p] + (float)(xx * 8 + 4);
        float ky = bases_full[(size_t)(NBASES + 2 * k + 1) * HW + p] + (float)(yy * 8 + 4);
        kp_out[((size_t)n * NKP + k) * 2 + 0] = kx;
        kp_out[((size_t)n * NKP + k) * 2 + 1] = ky;
    }
}

extern "C" void kernel_launch(void* const* d_in, const int* in_sizes, int n_in,
                              void* d_out, int out_size, void* d_ws, size_t ws_size,
                              hipStream_t stream) {
    const float* bases_full = (const float*)d_in[0];
    const float* top_feats  = (const float*)d_in[1];
    const float* locations  = (const float*)d_in[2];
    const float* atten_W    = (const float*)d_in[3];
    const float* atten_b    = (const float*)d_in[4];
    const float* soi        = (const float*)d_in[5];
    const int*   fpn        = (const int*)d_in[6];
    float* out   = (float*)d_out;
    float* attns = (float*)d_ws;
    unsigned long long* partial = (unsigned long long*)((char*)d_ws + PART_OFF);

    init_attn<<<(NI * AL + 255) / 256, 256, 0, stream>>>(atten_b, attns);
    gemm_attn<<<NJT * KSPLIT, 256, 0, stream>>>(top_feats, atten_W, attns);

    dim3 g2(NBX, NI);   // 30 x 64
    pixel_head<<<g2, 256, 0, stream>>>(bases_full, attns, locations, soi, fpn, out, partial);

    float* kp_out = out + (size_t)NI * NKP * HW;
    kp_final<<<NI * NKP, 64, 0, stream>>>(partial, bases_full, kp_out);
}